// Round 1
// baseline (308.838 us; speedup 1.0000x reference)
//
#include <hip/hip_runtime.h>
#include <hip/hip_bf16.h>

#define TOKENS 4096
#define IN_F   4096
#define OUT_F  4096

typedef __bf16 bf16x8 __attribute__((ext_vector_type(8)));
typedef float  f32x4  __attribute__((ext_vector_type(4)));
typedef unsigned int u32;

__device__ __forceinline__ void gld_lds16(const void* g, void* l) {
    __builtin_amdgcn_global_load_lds(
        (const __attribute__((address_space(1))) u32*)g,
        (__attribute__((address_space(3))) u32*)l,
        16, 0, 0);
}

// ---------------------------------------------------------------------------
// 1) Dequantize packed int4 -> bf16 W[n][k] row-major (4096 x 4096).
//    One thread per packed int32 (8 nibbles, all in the same group since
//    group = (p*8)/128 = p/16). 16B vector store.
// ---------------------------------------------------------------------------
__global__ __launch_bounds__(256) void dequant_kernel(
        const u32* __restrict__ qweight, const u32* __restrict__ qzeros,
        const float* __restrict__ scales, __bf16* __restrict__ W) {
    int idx = blockIdx.x * 256 + threadIdx.x;   // 0 .. 4096*512-1
    int n = idx >> 9;                           // out row
    int p = idx & 511;                          // packed col
    int g = p >> 4;                             // group id (0..31)
    u32 qw = qweight[idx];
    u32 qz = qzeros[(n << 2) + (g >> 3)];
    float z = (float)((qz >> ((g & 7) * 4)) & 15);
    float s = scales[(n << 5) + g];
    bf16x8 h;
#pragma unroll
    for (int j = 0; j < 8; ++j) {
        float w = ((float)((qw >> (4 * j)) & 15) - z) * s;
        h[j] = (__bf16)w;
    }
    *((bf16x8*)W + idx) = h;
}

// ---------------------------------------------------------------------------
// 2) Convert x fp32 -> bf16 (row-major A[m][k]). 8 elements/thread.
// ---------------------------------------------------------------------------
__global__ __launch_bounds__(256) void cvt_kernel(
        const float* __restrict__ x, __bf16* __restrict__ A) {
    int idx = blockIdx.x * 256 + threadIdx.x;   // 0 .. 4096*4096/8-1
    const f32x4* xp = (const f32x4*)x + (size_t)idx * 2;
    f32x4 a = xp[0], b = xp[1];
    bf16x8 h;
#pragma unroll
    for (int j = 0; j < 4; ++j) { h[j] = (__bf16)a[j]; h[4 + j] = (__bf16)b[j]; }
    *((bf16x8*)A + idx) = h;
}

// ---------------------------------------------------------------------------
// 3) GEMM: C[m][n] = sum_k A[m][k]*B[n][k] + bias[n]   (B^T-input form)
//    m97 structure: 128x128 tile, BK=32, 256 threads (4 waves, 2x2 of 64x64),
//    mfma_f32_16x16x32_bf16 4x4 per wave, global_load_lds width=16 staging.
// ---------------------------------------------------------------------------
__global__ __launch_bounds__(256) void gemm_bt(
        const __bf16* __restrict__ A, const __bf16* __restrict__ B,
        const float* __restrict__ bias, float* __restrict__ C) {
    __shared__ __align__(16) __bf16 lsA[128 * 32];
    __shared__ __align__(16) __bf16 lsB[128 * 32];

    const int t    = threadIdx.x;
    const int bm   = blockIdx.y, bn = blockIdx.x;
    const int lane = t & 63, wave = t >> 6;
    const int wm   = (wave >> 1) * 64;     // wave row offset in tile
    const int wn   = (wave & 1) * 64;      // wave col offset in tile
    const int lr   = lane & 15;            // row-in-16 for A/B fragments
    const int kq   = (lane >> 4) * 8;      // k offset (quad*8)

    const __bf16* Abase = A + (size_t)bm * 128 * IN_F;
    const __bf16* Bbase = B + (size_t)bn * 128 * IN_F;

    // staging: 128x32 bf16 tile = 512 x 16B chunks; thread t does chunks t, t+256
    // chunk q -> tile row q>>2, col (q&3)*8; LDS byte offset q*16 (wave-uniform
    // base + lane*16 — layout must stay contiguous, NO padding).
    const int q0 = t, q1 = t + 256;
    const int ar0 = q0 >> 2, ac0 = (q0 & 3) * 8;
    const int ar1 = q1 >> 2, ac1 = (q1 & 3) * 8;

    f32x4 acc[4][4] = {};

    for (int k0 = 0; k0 < IN_F; k0 += 32) {
        gld_lds16(Abase + (size_t)ar0 * IN_F + k0 + ac0, (char*)lsA + q0 * 16);
        gld_lds16(Abase + (size_t)ar1 * IN_F + k0 + ac1, (char*)lsA + q1 * 16);
        gld_lds16(Bbase + (size_t)ar0 * IN_F + k0 + ac0, (char*)lsB + q0 * 16);
        gld_lds16(Bbase + (size_t)ar1 * IN_F + k0 + ac1, (char*)lsB + q1 * 16);
        __syncthreads();

        bf16x8 af[4], bf[4];
#pragma unroll
        for (int i = 0; i < 4; ++i) {
            af[i] = *(const bf16x8*)(lsA + (wm + i * 16 + lr) * 32 + kq);
            bf[i] = *(const bf16x8*)(lsB + (wn + i * 16 + lr) * 32 + kq);
        }
#pragma unroll
        for (int i = 0; i < 4; ++i)
#pragma unroll
            for (int j = 0; j < 4; ++j)
                acc[i][j] = __builtin_amdgcn_mfma_f32_16x16x32_bf16(
                    af[i], bf[j], acc[i][j], 0, 0, 0);
        __syncthreads();
    }

    // epilogue: C/D layout col = lane&15, row = (lane>>4)*4 + reg
    const int quad = lane >> 4;
    const int row0 = bm * 128 + wm + quad * 4;
    const int col0 = bn * 128 + wn + lr;
#pragma unroll
    for (int j = 0; j < 4; ++j) {
        const int col = col0 + j * 16;
        const float bv = bias[col];
#pragma unroll
        for (int i = 0; i < 4; ++i) {
            const int row = row0 + i * 16;
#pragma unroll
            for (int r = 0; r < 4; ++r)
                C[(size_t)(row + r) * OUT_F + col] = acc[i][j][r] + bv;
        }
    }
}

extern "C" void kernel_launch(void* const* d_in, const int* in_sizes, int n_in,
                              void* d_out, int out_size, void* d_ws, size_t ws_size,
                              hipStream_t stream) {
    (void)in_sizes; (void)n_in; (void)out_size; (void)ws_size;
    const float* x       = (const float*)d_in[0];
    const u32*   qweight = (const u32*)d_in[1];
    const u32*   qzeros  = (const u32*)d_in[2];
    const float* scales  = (const float*)d_in[3];
    const float* bias    = (const float*)d_in[4];
    float* out = (float*)d_out;

    __bf16* W   = (__bf16*)d_ws;                                   // 32 MB
    __bf16* Abf = (__bf16*)((char*)d_ws + (size_t)OUT_F * IN_F * 2); // 32 MB

    dequant_kernel<<<dim3(OUT_F * (IN_F / 8) / 256), dim3(256), 0, stream>>>(
        qweight, qzeros, scales, W);
    cvt_kernel<<<dim3(TOKENS * IN_F / 8 / 256), dim3(256), 0, stream>>>(x, Abf);
    gemm_bt<<<dim3(OUT_F / 128, TOKENS / 128), dim3(256), 0, stream>>>(
        Abf, W, bias, out);
}